// Round 1
// 419.073 us; speedup vs baseline: 1.0007x; 1.0007x over previous
//
#include <hip/hip_runtime.h>

#define BB 64
#define KK 8
#define VV 128000
#define TILE 1024
#define NTILES 125          // VV / TILE
#define SPLIT 8
#define TPS 16              // tiles per split block (last split gets 13)
#define NWAVES 8            // waves per pass_a block (512 threads)
#define PLACEHOLDER (-1)

// d_ws word layout (4-byte words)
#define WS_TSUM 0                              // [BB][NTILES] float
#define WS_AV   (BB * NTILES)                  // [BB][SPLIT*NWAVES] float (per-wave argmax val)
#define WS_AI   (WS_AV + BB * SPLIT * NWAVES)  // [BB][SPLIT*NWAVES] int   (per-wave argmax idx)
#define WS_NA   (WS_AI + BB * SPLIT * NWAVES)  // [BB] int                 (num accepted per batch)

// Uniform-per-block accept logic: every thread recomputes it (all loads hit the
// same cache lines; ~2 dependent HBM round trips).
__device__ __forceinline__ int accept_na(const int* __restrict__ draft_ids,
                                         const float* __restrict__ draft_probs,
                                         const float* __restrict__ target_probs,
                                         const float* __restrict__ uniforms, int b) {
    int   ids[KK];
    float us[KK], ps[KK], qs[KK];
#pragma unroll
    for (int k = 0; k < KK; ++k) ids[k] = draft_ids[b * KK + k];
#pragma unroll
    for (int k = 0; k < KK; ++k) us[k] = uniforms[b * KK + k];
#pragma unroll
    for (int k = 0; k < KK; ++k) {
        long r = (long)(b * KK + k) * VV + ids[k];
        ps[k]  = target_probs[r];
        qs[k]  = draft_probs[r];
    }
    int  na  = 0;
    bool run = true;
#pragma unroll
    for (int k = 0; k < KK; ++k) {
        bool acc = us[k] < fminf(1.0f, ps[k] / fmaxf(qs[k], 1e-10f));
        run      = run && acc;
        na += run ? 1 : 0;
    }
    return na;
}

// Pass A: 512 blocks (8 splits x 64 batches), 512 threads (8 waves).
// Wave w sums tiles t0 + w + 8*i (i=0,1) — wave-private, no __syncthreads.
// 16 waves/CU resident (vs 8 before) to raise outstanding-load count toward BW peak.
__global__ __launch_bounds__(512) void pass_a_kernel(
    const int* __restrict__ draft_ids, const float* __restrict__ draft_probs,
    const float* __restrict__ target_probs, const float* __restrict__ uniforms,
    float* __restrict__ ws_f, int* __restrict__ ws_i) {
    const int s    = blockIdx.x;
    const int b    = blockIdx.y;
    const int tid  = threadIdx.x;
    const int lane = tid & 63;
    const int w    = tid >> 6;

    int na = accept_na(draft_ids, draft_probs, target_probs, uniforms, b);
    if (s == 0 && tid == 0) ws_i[WS_NA + b] = na;  // publish for finalize
    if (na == KK) return;  // all-accept: finalize never reads our tsum/argmax region
    int j = na < (KK - 1) ? na : (KK - 1);

    const float* __restrict__ tgt = target_probs + (long)(b * KK + j) * VV;
    const float* __restrict__ drf = draft_probs + (long)(b * KK + j) * VV;

    float mval = -1.0f;
    int   midx = 0;
    const int t0 = s * TPS;
#pragma unroll
    for (int i = 0; i < 2; ++i) {
        int t = t0 + w + NWAVES * i;  // wave-uniform condition below
        if (t >= NTILES) continue;
        float ssum = 0.0f;
#pragma unroll
        for (int g = 0; g < 4; ++g) {
            int    off = t * TILE + g * 256 + lane * 4;
            float4 tv  = *(const float4*)(tgt + off);
            float4 dv  = *(const float4*)(drf + off);
            ssum += fmaxf(tv.x - dv.x, 0.0f) + fmaxf(tv.y - dv.y, 0.0f) +
                    fmaxf(tv.z - dv.z, 0.0f) + fmaxf(tv.w - dv.w, 0.0f);
            if (tv.x > mval) { mval = tv.x; midx = off; }
            if (tv.y > mval) { mval = tv.y; midx = off + 1; }
            if (tv.z > mval) { mval = tv.z; midx = off + 2; }
            if (tv.w > mval) { mval = tv.w; midx = off + 3; }
        }
        for (int o = 32; o > 0; o >>= 1) ssum += __shfl_xor(ssum, o, 64);
        if (lane == 0) ws_f[WS_TSUM + b * NTILES + t] = ssum;
    }
    // per-wave argmax partial (for the total<=0 fallback).
    // Every wave has >=1 valid tile (splits 0..6 full; split 7 i=0 covers 112..119).
    for (int o = 32; o > 0; o >>= 1) {
        float ov = __shfl_xor(mval, o, 64);
        int   oi = __shfl_xor(midx, o, 64);
        if (ov > mval || (ov == mval && oi < midx)) { mval = ov; midx = oi; }
    }
    if (lane == 0) {
        ws_f[WS_AV + b * SPLIT * NWAVES + s * NWAVES + w] = mval;
        ws_i[WS_AI + b * SPLIT * NWAVES + s * NWAVES + w] = midx;
    }
}

// Finalize: 64 blocks x 64 threads (1 wave per batch row).
// Reads na from ws (no recompute) and issues tile-sum loads before consuming na.
__global__ __launch_bounds__(64) void finalize_kernel(
    const int* __restrict__ draft_ids, const float* __restrict__ draft_probs,
    const float* __restrict__ target_probs, const int* __restrict__ bonus_ids,
    const float* __restrict__ uniforms, const float* __restrict__ ws_f,
    const int* __restrict__ ws_i, int* __restrict__ out) {
    const int b    = blockIdx.x;
    const int lane = threadIdx.x;

    __shared__ float s_ts[NTILES];
    __shared__ float s_total, s_thr, s_P;
    __shared__ int   s_ct;

    // issue independent loads first (tile sums are poison for all-accept rows; discarded)
    float ts0 = ws_f[WS_TSUM + b * NTILES + lane];
    float ts1 = 0.0f;
    if (lane < NTILES - 64) ts1 = ws_f[WS_TSUM + b * NTILES + lane + 64];

    int na  = ws_i[WS_NA + b];
    int all = (na == KK) ? 1 : 0;
    int j   = na < (KK - 1) ? na : (KK - 1);

    // token row: skip pos==na when !all — the recovered write fills it (no overwrite hazard)
    if (lane <= KK) {
        bool wr = true;
        int  v;
        if (lane < na) v = draft_ids[b * KK + lane];
        else if (lane == na) { if (all) v = bonus_ids[b]; else wr = false; }
        else v = PLACEHOLDER;
        if (wr) out[b * (KK + 1) + lane] = v;
    }
    if (lane == 0) {
        out[BB * (KK + 1) + b]          = na;
        out[BB * (KK + 1) + BB + b]     = na;
        out[BB * (KK + 1) + 2 * BB + b] = 1 - all;
        out[BB * (KK + 1) + 3 * BB + b] = all;
    }
    if (all) return;  // whole block is one wave; uniform exit before any __syncthreads

    s_ts[lane] = ts0;
    if (lane < NTILES - 64) s_ts[lane + 64] = ts1;
    __syncthreads();

    if (lane == 0) {
        float u_j   = uniforms[b * KK + j];
        float total = 0.0f;
        for (int t = 0; t < NTILES; ++t) total += s_ts[t];
        float thr = u_j * total;
        float run = 0.0f;
        int   ct  = -1;
        float P   = 0.0f;
        for (int t = 0; t < NTILES; ++t) {
            if (run + s_ts[t] > thr) { ct = t; P = run; break; }
            run += s_ts[t];
        }
        s_total = total; s_thr = thr; s_P = P; s_ct = ct;
    }
    __syncthreads();

    const float total = s_total, thr = s_thr, P = s_P;
    const int   ct    = s_ct;
    int rec;
    if (total > 0.0f) {
        if (ct < 0) {
            rec = VV - 1;  // rounding pushed thr >= total
        } else {
            const float* __restrict__ tgt = target_probs + (long)(b * KK + j) * VV;
            const float* __restrict__ drf = draft_probs + (long)(b * KK + j) * VV;
            float G     = 0.0f;
            int   cand  = 0x7fffffff;
            int   tbase = ct * TILE;
#pragma unroll
            for (int g = 0; g < 4; ++g) {
                int    off = tbase + g * 256 + lane * 4;
                float4 tv  = *(const float4*)(tgt + off);
                float4 dv  = *(const float4*)(drf + off);
                float  r0  = fmaxf(tv.x - dv.x, 0.0f);
                float  r1  = fmaxf(tv.y - dv.y, 0.0f);
                float  r2  = fmaxf(tv.z - dv.z, 0.0f);
                float  r3  = fmaxf(tv.w - dv.w, 0.0f);
                float  ls  = r0 + r1 + r2 + r3;
                float  inc = ls;
                for (int o = 1; o < 64; o <<= 1) {
                    float n = __shfl_up(inc, o, 64);
                    if (lane >= o) inc += n;
                }
                float lex  = inc - ls;
                float runp = P + G + lex;
                float p0 = runp + r0, p1 = p0 + r1, p2 = p1 + r2, p3 = p2 + r3;
                int   c  = 0x7fffffff;
                if (p3 > thr) c = off + 3;
                if (p2 > thr) c = off + 2;
                if (p1 > thr) c = off + 1;
                if (p0 > thr) c = off;
                cand = min(cand, c);
                G += __shfl(inc, 63, 64);
            }
            for (int o = 32; o > 0; o >>= 1) cand = min(cand, __shfl_xor(cand, o, 64));
            rec = (cand == 0x7fffffff) ? (tbase + TILE - 1) : cand;
        }
    } else {
        // fallback: argmax of tgt row from the 64 per-wave partials
        float v = ws_f[WS_AV + b * SPLIT * NWAVES + lane];
        int   i = ws_i[WS_AI + b * SPLIT * NWAVES + lane];
        for (int o = 32; o > 0; o >>= 1) {
            float ov = __shfl_xor(v, o, 64);
            int   oi = __shfl_xor(i, o, 64);
            if (ov > v || (ov == v && oi < i)) { v = ov; i = oi; }
        }
        rec = i;
    }
    if (lane == 0) out[b * (KK + 1) + na] = rec;
}

extern "C" void kernel_launch(void* const* d_in, const int* in_sizes, int n_in,
                              void* d_out, int out_size, void* d_ws, size_t ws_size,
                              hipStream_t stream) {
    const int*   draft_ids    = (const int*)d_in[0];
    const float* draft_probs  = (const float*)d_in[1];
    const float* target_probs = (const float*)d_in[2];
    const int*   bonus_ids    = (const int*)d_in[3];
    const float* uniforms     = (const float*)d_in[4];
    int*         out          = (int*)d_out;
    float*       ws_f         = (float*)d_ws;
    int*         ws_i         = (int*)d_ws;

    pass_a_kernel<<<dim3(SPLIT, BB), 512, 0, stream>>>(draft_ids, draft_probs,
                                                       target_probs, uniforms, ws_f, ws_i);
    finalize_kernel<<<BB, 64, 0, stream>>>(draft_ids, draft_probs, target_probs,
                                           bonus_ids, uniforms, ws_f, ws_i, out);
}